// Round 1
// baseline (1107.057 us; speedup 1.0000x reference)
//
#include <hip/hip_runtime.h>
#include <hip/hip_bf16.h>
#include <float.h>

// Problem constants (from reference)
#define N_NODES 20000
#define LATENT  512
#define HID     256
#define OUT_C   128
#define HEADS   2
#define HC      256   // HEADS*OUT_C
#define NEG_SLOPE 0.2f

// ---------------------------------------------------------------------------
// float atomicMax via int/uint trick (standard, correct for mixed signs)
__device__ __forceinline__ void atomicMaxFloat(float* addr, float value) {
    if (value >= 0.f)
        atomicMax((int*)addr, __float_as_int(value));
    else
        atomicMin((unsigned int*)addr, __float_as_uint(value));
}

// ---------------------------------------------------------------------------
// Tiled fp32 GEMM: C[M,N] = act(A[M,K] @ B[K,N] + bias)
// 64x64 tile per block, 256 threads, 4x4 micro-tile per thread, BK=16.
__global__ __launch_bounds__(256) void sgemm_bias_act(
    const float* __restrict__ A, const float* __restrict__ B,
    const float* __restrict__ bias, float* __restrict__ C,
    int M, int N, int K, int relu)
{
    __shared__ float s_a[16][68];   // padded: avoids 4-way store conflicts
    __shared__ float s_b[16][64];

    const int tid = threadIdx.x;
    const int tx = tid & 15, ty = tid >> 4;
    const int row0 = blockIdx.x * 64;
    const int col0 = blockIdx.y * 64;

    const int ar = tid >> 2;           // 0..63  (A tile row)
    const int ac = (tid & 3) << 2;     // 0,4,8,12 (A tile col, float4)
    const int br = tid >> 4;           // 0..15  (B tile row)
    const int bc = (tid & 15) << 2;    // 0..60  (B tile col, float4)

    const bool a_ok = (row0 + ar) < M;
    const float* Aptr = A + (size_t)(row0 + ar) * K + ac;
    const float* Bptr = B + (size_t)br * N + col0 + bc;

    float acc[4][4] = {};

    for (int k0 = 0; k0 < K; k0 += 16) {
        float4 av = make_float4(0.f, 0.f, 0.f, 0.f);
        if (a_ok) av = *(const float4*)(Aptr + k0);
        s_a[ac + 0][ar] = av.x;
        s_a[ac + 1][ar] = av.y;
        s_a[ac + 2][ar] = av.z;
        s_a[ac + 3][ar] = av.w;

        float4 bv = *(const float4*)(Bptr + (size_t)k0 * N);
        *(float4*)(&s_b[br][bc]) = bv;

        __syncthreads();

        #pragma unroll
        for (int k = 0; k < 16; ++k) {
            float a0 = s_a[k][ty * 4 + 0];
            float a1 = s_a[k][ty * 4 + 1];
            float a2 = s_a[k][ty * 4 + 2];
            float a3 = s_a[k][ty * 4 + 3];
            float b0 = s_b[k][tx * 4 + 0];
            float b1 = s_b[k][tx * 4 + 1];
            float b2 = s_b[k][tx * 4 + 2];
            float b3 = s_b[k][tx * 4 + 3];
            acc[0][0] += a0 * b0; acc[0][1] += a0 * b1; acc[0][2] += a0 * b2; acc[0][3] += a0 * b3;
            acc[1][0] += a1 * b0; acc[1][1] += a1 * b1; acc[1][2] += a1 * b2; acc[1][3] += a1 * b3;
            acc[2][0] += a2 * b0; acc[2][1] += a2 * b1; acc[2][2] += a2 * b2; acc[2][3] += a2 * b3;
            acc[3][0] += a3 * b0; acc[3][1] += a3 * b1; acc[3][2] += a3 * b2; acc[3][3] += a3 * b3;
        }
        __syncthreads();
    }

    #pragma unroll
    for (int i = 0; i < 4; ++i) {
        int r = row0 + ty * 4 + i;
        if (r >= M) continue;
        #pragma unroll
        for (int j = 0; j < 4; ++j) {
            int c = col0 + tx * 4 + j;
            float v = acc[i][j];
            if (bias) v += bias[c];
            if (relu) v = fmaxf(v, 0.f);
            C[(size_t)r * N + c] = v;
        }
    }
}

// ---------------------------------------------------------------------------
// a_src[n,h] = dot(xp[n,h,:], att_src[h,:]); a_dst likewise. One wave per (n,h).
__global__ __launch_bounds__(256) void att_kernel(
    const float* __restrict__ xp, const float* __restrict__ att_src,
    const float* __restrict__ att_dst,
    float* __restrict__ a_src, float* __restrict__ a_dst, int n)
{
    int gw = (blockIdx.x * blockDim.x + threadIdx.x) >> 6;  // global wave id
    int lane = threadIdx.x & 63;
    if (gw >= 2 * n) return;
    int node = gw >> 1, h = gw & 1;
    const float* row = xp + (size_t)node * HC + h * OUT_C;
    const float* as = att_src + h * OUT_C;
    const float* ad = att_dst + h * OUT_C;
    float s1 = row[lane] * as[lane] + row[lane + 64] * as[lane + 64];
    float s2 = row[lane] * ad[lane] + row[lane + 64] * ad[lane + 64];
    #pragma unroll
    for (int off = 32; off > 0; off >>= 1) {
        s1 += __shfl_down(s1, off);
        s2 += __shfl_down(s2, off);
    }
    if (lane == 0) { a_src[gw] = s1; a_dst[gw] = s2; }
}

// ---------------------------------------------------------------------------
// Init: amax=-inf, denom=0, outacc=0 (ws is poisoned 0xAA before every call)
__global__ void init_gat(float* amax, float* denom, float* outacc,
                         int n_nh, size_t n_acc)
{
    size_t i = (size_t)blockIdx.x * blockDim.x + threadIdx.x;
    if (i < n_acc) outacc[i] = 0.f;
    if (i < (size_t)n_nh) { amax[i] = -FLT_MAX; denom[i] = 0.f; }
}

// ---------------------------------------------------------------------------
// Pass 1 over edges (incl. self loops): alpha = leaky_relu(a_src[s]+a_dst[d]);
// store alpha, atomicMax into amax[d,h]. One thread per (edge, head).
__global__ __launch_bounds__(256) void edge_alpha_kernel(
    const int* __restrict__ src, const int* __restrict__ dst,
    const float* __restrict__ a_src, const float* __restrict__ a_dst,
    float* __restrict__ alpha, float* amax, int E_real, int ET)
{
    int i = blockIdx.x * blockDim.x + threadIdx.x;
    if (i >= 2 * ET) return;
    int e = i >> 1, h = i & 1;
    int s, d;
    if (e < E_real) { s = src[e]; d = dst[e]; }
    else            { s = e - E_real; d = s; }   // self loop
    float a = a_src[2 * s + h] + a_dst[2 * d + h];
    a = (a > 0.f) ? a : NEG_SLOPE * a;
    alpha[i] = a;
    atomicMaxFloat(&amax[2 * d + h], a);
}

// ---------------------------------------------------------------------------
// Pass 2: w = exp(alpha - amax[d]); denom[d,h] += w;
// outacc[d,:] += w * xp[s,:]  (normalization deferred to finalize).
// One block (256 threads) per edge; thread t handles channel t (h = t>>7).
__global__ __launch_bounds__(256) void edge_accum_kernel(
    const int* __restrict__ src, const int* __restrict__ dst,
    const float* __restrict__ alpha, const float* __restrict__ amax,
    const float* __restrict__ xp,
    float* outacc, float* denom, int E_real)
{
    int e = blockIdx.x;
    int t = threadIdx.x;
    int s, d;
    if (e < E_real) { s = src[e]; d = dst[e]; }
    else            { s = e - E_real; d = s; }
    int h = t >> 7;
    float w = expf(alpha[2 * e + h] - amax[2 * d + h]);
    if (t == 0 || t == 128)
        atomicAdd(&denom[2 * d + h], w);
    atomicAdd(&outacc[(size_t)d * HC + t], w * xp[(size_t)s * HC + t]);
}

// ---------------------------------------------------------------------------
// xg[n,t] = outacc[n,t] / max(denom[n,h], 1e-16) + bias_g[t]
__global__ __launch_bounds__(256) void finalize_kernel(
    const float* __restrict__ outacc, const float* __restrict__ denom,
    const float* __restrict__ bias_g, float* __restrict__ xg, int n)
{
    int i = blockIdx.x * 256 + threadIdx.x;
    int node = i >> 8, t = i & 255, h = t >> 7;
    (void)n;
    float dn = fmaxf(denom[2 * node + h], 1e-16f);
    xg[i] = outacc[i] / dn + bias_g[t];
}

// ---------------------------------------------------------------------------
extern "C" void kernel_launch(void* const* d_in, const int* in_sizes, int n_in,
                              void* d_out, int out_size, void* d_ws, size_t ws_size,
                              hipStream_t stream)
{
    const float* z       = (const float*)d_in[0];
    const int*   ei      = (const int*)d_in[1];    // [2,E] int32
    const float* W1      = (const float*)d_in[2];
    const float* b1      = (const float*)d_in[3];
    const float* W2      = (const float*)d_in[4];
    const float* b2      = (const float*)d_in[5];
    const float* Wg      = (const float*)d_in[6];
    const float* att_src = (const float*)d_in[7];
    const float* att_dst = (const float*)d_in[8];
    const float* bias_g  = (const float*)d_in[9];
    const float* W3      = (const float*)d_in[10];
    const float* b3      = (const float*)d_in[11];
    float* out = (float*)d_out;

    const int n = N_NODES;
    const int E_real = in_sizes[1] / 2;
    const int ET = E_real + n;                 // edges + self loops
    const int* src = ei;
    const int* dst = ei + E_real;

    // Workspace layout (floats). outacc aliases x2, xg aliases x1
    // (both dead by the time the alias is written).
    float* ws = (float*)d_ws;
    size_t o = 0;
    float* x1    = ws + o; o += (size_t)n * HID;     // 5.12M  (z@W1 relu)
    float* x2    = ws + o; o += (size_t)n * 512;     // 10.24M (x1@W2 relu)
    float* xp    = ws + o; o += (size_t)n * HC;      // 5.12M  (x2@Wg)
    float* a_src = ws + o; o += (size_t)2 * n;
    float* a_dst = ws + o; o += (size_t)2 * n;
    float* amax  = ws + o; o += (size_t)2 * n;
    float* denom = ws + o; o += (size_t)2 * n;
    float* alpha = ws + o; o += (size_t)2 * ET;      // 1.32M
    float* outacc = x2;    // reuse (x2 dead after GEMM3)
    float* xg     = x1;    // reuse (x1 dead after GEMM2)

    const int gm = (n + 63) / 64;   // 313

    // x1 = relu(z @ W1 + b1)            [20000,512]@[512,256]
    sgemm_bias_act<<<dim3(gm, HID / 64), 256, 0, stream>>>(
        z, W1, b1, x1, n, HID, LATENT, 1);
    // x2 = relu(x1 @ W2 + b2)           [20000,256]@[256,512]
    sgemm_bias_act<<<dim3(gm, 512 / 64), 256, 0, stream>>>(
        x1, W2, b2, x2, n, 512, HID, 1);
    // xp = x2 @ Wg                      [20000,512]@[512,256]
    sgemm_bias_act<<<dim3(gm, HC / 64), 256, 0, stream>>>(
        x2, Wg, nullptr, xp, n, HC, 512, 0);
    // attention logits per (node, head)
    att_kernel<<<(2 * n + 3) / 4, 256, 0, stream>>>(
        xp, att_src, att_dst, a_src, a_dst, n);
    // init accumulators (after GEMM3: outacc aliases x2)
    init_gat<<<n, 256, 0, stream>>>(amax, denom, outacc, 2 * n, (size_t)n * HC);
    // softmax pass 1: leaky_relu + segment max
    edge_alpha_kernel<<<(2 * ET + 255) / 256, 256, 0, stream>>>(
        src, dst, a_src, a_dst, alpha, amax, E_real, ET);
    // softmax pass 2 + weighted message scatter
    edge_accum_kernel<<<ET, 256, 0, stream>>>(
        src, dst, alpha, amax, xp, outacc, denom, E_real);
    // normalize + bias_g
    finalize_kernel<<<n, 256, 0, stream>>>(outacc, denom, bias_g, xg, n);
    // out = xg @ W3 + b3                [20000,256]@[256,512]
    sgemm_bias_act<<<dim3(gm, 512 / 64), 256, 0, stream>>>(
        xg, W3, b3, out, n, 512, HC, 0);
}

// Round 2
// 658.580 us; speedup vs baseline: 1.6810x; 1.6810x over previous
//
#include <hip/hip_runtime.h>
#include <hip/hip_bf16.h>
#include <float.h>

// Problem constants (from reference)
#define N_NODES 20000
#define LATENT  512
#define HID     256
#define OUT_C   128
#define HEADS   2
#define HC      256   // HEADS*OUT_C
#define NEG_SLOPE 0.2f

// ---------------------------------------------------------------------------
// Tiled fp32 GEMM: C[M,N] = act(A[M,K] @ B[K,N] + bias)
// 64x64 tile per block, 256 threads, 4x4 micro-tile per thread, BK=16.
__global__ __launch_bounds__(256) void sgemm_bias_act(
    const float* __restrict__ A, const float* __restrict__ B,
    const float* __restrict__ bias, float* __restrict__ C,
    int M, int N, int K, int relu)
{
    __shared__ float s_a[16][68];   // padded: avoids 4-way store conflicts
    __shared__ float s_b[16][64];

    const int tid = threadIdx.x;
    const int tx = tid & 15, ty = tid >> 4;
    const int row0 = blockIdx.x * 64;
    const int col0 = blockIdx.y * 64;

    const int ar = tid >> 2;           // 0..63  (A tile row)
    const int ac = (tid & 3) << 2;     // 0,4,8,12 (A tile col, float4)
    const int br = tid >> 4;           // 0..15  (B tile row)
    const int bc = (tid & 15) << 2;    // 0..60  (B tile col, float4)

    const bool a_ok = (row0 + ar) < M;
    const float* Aptr = A + (size_t)(row0 + ar) * K + ac;
    const float* Bptr = B + (size_t)br * N + col0 + bc;

    float acc[4][4] = {};

    for (int k0 = 0; k0 < K; k0 += 16) {
        float4 av = make_float4(0.f, 0.f, 0.f, 0.f);
        if (a_ok) av = *(const float4*)(Aptr + k0);
        s_a[ac + 0][ar] = av.x;
        s_a[ac + 1][ar] = av.y;
        s_a[ac + 2][ar] = av.z;
        s_a[ac + 3][ar] = av.w;

        float4 bv = *(const float4*)(Bptr + (size_t)k0 * N);
        *(float4*)(&s_b[br][bc]) = bv;

        __syncthreads();

        #pragma unroll
        for (int k = 0; k < 16; ++k) {
            float a0 = s_a[k][ty * 4 + 0];
            float a1 = s_a[k][ty * 4 + 1];
            float a2 = s_a[k][ty * 4 + 2];
            float a3 = s_a[k][ty * 4 + 3];
            float b0 = s_b[k][tx * 4 + 0];
            float b1 = s_b[k][tx * 4 + 1];
            float b2 = s_b[k][tx * 4 + 2];
            float b3 = s_b[k][tx * 4 + 3];
            acc[0][0] += a0 * b0; acc[0][1] += a0 * b1; acc[0][2] += a0 * b2; acc[0][3] += a0 * b3;
            acc[1][0] += a1 * b0; acc[1][1] += a1 * b1; acc[1][2] += a1 * b2; acc[1][3] += a1 * b3;
            acc[2][0] += a2 * b0; acc[2][1] += a2 * b1; acc[2][2] += a2 * b2; acc[2][3] += a2 * b3;
            acc[3][0] += a3 * b0; acc[3][1] += a3 * b1; acc[3][2] += a3 * b2; acc[3][3] += a3 * b3;
        }
        __syncthreads();
    }

    #pragma unroll
    for (int i = 0; i < 4; ++i) {
        int r = row0 + ty * 4 + i;
        if (r >= M) continue;
        #pragma unroll
        for (int j = 0; j < 4; ++j) {
            int c = col0 + tx * 4 + j;
            float v = acc[i][j];
            if (bias) v += bias[c];
            if (relu) v = fmaxf(v, 0.f);
            C[(size_t)r * N + c] = v;
        }
    }
}

// ---------------------------------------------------------------------------
// a_src[n,h] = dot(xp[n,h,:], att_src[h,:]); a_dst likewise. One wave per (n,h).
__global__ __launch_bounds__(256) void att_kernel(
    const float* __restrict__ xp, const float* __restrict__ att_src,
    const float* __restrict__ att_dst,
    float* __restrict__ a_src, float* __restrict__ a_dst, int n)
{
    int gw = (blockIdx.x * blockDim.x + threadIdx.x) >> 6;  // global wave id
    int lane = threadIdx.x & 63;
    if (gw >= 2 * n) return;
    int node = gw >> 1, h = gw & 1;
    const float* row = xp + (size_t)node * HC + h * OUT_C;
    const float* as = att_src + h * OUT_C;
    const float* ad = att_dst + h * OUT_C;
    float s1 = row[lane] * as[lane] + row[lane + 64] * as[lane + 64];
    float s2 = row[lane] * ad[lane] + row[lane + 64] * ad[lane + 64];
    #pragma unroll
    for (int off = 32; off > 0; off >>= 1) {
        s1 += __shfl_down(s1, off);
        s2 += __shfl_down(s2, off);
    }
    if (lane == 0) { a_src[gw] = s1; a_dst[gw] = s2; }
}

// ---------------------------------------------------------------------------
// Zero deg + cursor (ws is poisoned 0xAA before every call)
__global__ void zero_int2(int* deg, int* cursor, int n)
{
    int i = blockIdx.x * blockDim.x + threadIdx.x;
    if (i < n) { deg[i] = 0; cursor[i] = 0; }
}

// ---------------------------------------------------------------------------
// Histogram of dst (incl. self loops)
__global__ __launch_bounds__(256) void hist_kernel(
    const int* __restrict__ dst, int* deg, int E_real, int ET)
{
    int e = blockIdx.x * blockDim.x + threadIdx.x;
    if (e >= ET) return;
    int d = (e < E_real) ? dst[e] : (e - E_real);
    atomicAdd(&deg[d], 1);
}

// ---------------------------------------------------------------------------
// Exclusive scan deg[0..n) -> rowptr[0..n]; single block, 256 threads.
__global__ __launch_bounds__(256) void scan_kernel(
    const int* __restrict__ deg, int* __restrict__ rowptr, int n)
{
    __shared__ int part[256];
    __shared__ int scan[257];
    const int t = threadIdx.x;
    const int chunk = (n + 255) / 256;
    const int lo = t * chunk;
    const int hi = min(lo + chunk, n);
    int s = 0;
    for (int i = lo; i < hi; ++i) s += deg[i];
    part[t] = s;
    __syncthreads();
    if (t == 0) {
        int acc = 0;
        scan[0] = 0;
        for (int i = 0; i < 256; ++i) { acc += part[i]; scan[i + 1] = acc; }
    }
    __syncthreads();
    int run = scan[t];
    for (int i = lo; i < hi; ++i) { rowptr[i] = run; run += deg[i]; }
    if (t == 255) rowptr[n] = run;
}

// ---------------------------------------------------------------------------
// Scatter src ids into dst-sorted order
__global__ __launch_bounds__(256) void scatter_kernel(
    const int* __restrict__ src, const int* __restrict__ dst,
    const int* __restrict__ rowptr, int* cursor,
    int* __restrict__ sorted_src, int E_real, int ET)
{
    int e = blockIdx.x * blockDim.x + threadIdx.x;
    if (e >= ET) return;
    int s, d;
    if (e < E_real) { s = src[e]; d = dst[e]; }
    else            { s = e - E_real; d = s; }
    int pos = rowptr[d] + atomicAdd(&cursor[d], 1);
    sorted_src[pos] = s;
}

// ---------------------------------------------------------------------------
// One block per dst node: softmax over its incoming edges + weighted
// aggregation, fully in registers; fused normalize + bias_g.
// Thread t owns channel t (head h = t>>7).
__global__ __launch_bounds__(256) void gat_aggregate(
    const int* __restrict__ rowptr, const int* __restrict__ sorted_src,
    const float* __restrict__ a_src, const float* __restrict__ a_dst,
    const float* __restrict__ xp, const float* __restrict__ bias_g,
    float* __restrict__ xg)
{
    __shared__ float red0[256];
    __shared__ float red1[256];

    const int d = blockIdx.x;
    const int t = threadIdx.x;
    const int h = t >> 7;
    const int start = rowptr[d], end = rowptr[d + 1];

    const float ad0 = a_dst[2 * d + 0];
    const float ad1 = a_dst[2 * d + 1];

    // Phase A: per-head max of leaky_relu(a_src[s]+a_dst[d]) over edges
    float m0 = -FLT_MAX, m1 = -FLT_MAX;
    for (int e = start + t; e < end; e += 256) {
        int s = sorted_src[e];
        float v0 = a_src[2 * s + 0] + ad0;
        float v1 = a_src[2 * s + 1] + ad1;
        v0 = (v0 > 0.f) ? v0 : NEG_SLOPE * v0;
        v1 = (v1 > 0.f) ? v1 : NEG_SLOPE * v1;
        m0 = fmaxf(m0, v0);
        m1 = fmaxf(m1, v1);
    }
    red0[t] = m0; red1[t] = m1;
    __syncthreads();
    #pragma unroll
    for (int s = 128; s > 0; s >>= 1) {
        if (t < s) {
            red0[t] = fmaxf(red0[t], red0[t + s]);
            red1[t] = fmaxf(red1[t], red1[t + s]);
        }
        __syncthreads();
    }
    const float m = h ? red1[0] : red0[0];
    const float adh = h ? ad1 : ad0;

    // Phase B: every thread walks all edges; accumulate its channel + denom
    float acc = 0.f, denom = 0.f;
    for (int e = start; e < end; ++e) {
        int s = sorted_src[e];
        float a = a_src[2 * s + h] + adh;
        a = (a > 0.f) ? a : NEG_SLOPE * a;
        float w = expf(a - m);
        denom += w;
        acc += w * xp[(size_t)s * HC + t];
    }
    xg[(size_t)d * HC + t] = acc / fmaxf(denom, 1e-16f) + bias_g[t];
}

// ---------------------------------------------------------------------------
extern "C" void kernel_launch(void* const* d_in, const int* in_sizes, int n_in,
                              void* d_out, int out_size, void* d_ws, size_t ws_size,
                              hipStream_t stream)
{
    const float* z       = (const float*)d_in[0];
    const int*   ei      = (const int*)d_in[1];    // [2,E] int32
    const float* W1      = (const float*)d_in[2];
    const float* b1      = (const float*)d_in[3];
    const float* W2      = (const float*)d_in[4];
    const float* b2      = (const float*)d_in[5];
    const float* Wg      = (const float*)d_in[6];
    const float* att_src = (const float*)d_in[7];
    const float* att_dst = (const float*)d_in[8];
    const float* bias_g  = (const float*)d_in[9];
    const float* W3      = (const float*)d_in[10];
    const float* b3      = (const float*)d_in[11];
    float* out = (float*)d_out;

    const int n = N_NODES;
    const int E_real = in_sizes[1] / 2;
    const int ET = E_real + n;                 // edges + self loops
    const int* src = ei;
    const int* dst = ei + E_real;

    // Workspace layout. xg aliases x1 (dead after GEMM2).
    float* ws = (float*)d_ws;
    size_t o = 0;
    float* x1    = ws + o; o += (size_t)n * HID;     // 5.12M
    float* x2    = ws + o; o += (size_t)n * 512;     // 10.24M
    float* xp    = ws + o; o += (size_t)n * HC;      // 5.12M
    float* a_src = ws + o; o += (size_t)2 * n;
    float* a_dst = ws + o; o += (size_t)2 * n;
    int* deg        = (int*)(ws + o); o += (size_t)n;
    int* rowptr     = (int*)(ws + o); o += (size_t)n + 1;
    int* cursor     = (int*)(ws + o); o += (size_t)n;
    int* sorted_src = (int*)(ws + o); o += (size_t)ET;
    float* xg = x1;   // reuse

    const int gm = (n + 63) / 64;   // 313

    // x1 = relu(z @ W1 + b1)
    sgemm_bias_act<<<dim3(gm, HID / 64), 256, 0, stream>>>(
        z, W1, b1, x1, n, HID, LATENT, 1);
    // x2 = relu(x1 @ W2 + b2)
    sgemm_bias_act<<<dim3(gm, 512 / 64), 256, 0, stream>>>(
        x1, W2, b2, x2, n, 512, HID, 1);
    // xp = x2 @ Wg
    sgemm_bias_act<<<dim3(gm, HC / 64), 256, 0, stream>>>(
        x2, Wg, nullptr, xp, n, HC, 512, 0);
    // attention logits per (node, head)
    att_kernel<<<(2 * n + 3) / 4, 256, 0, stream>>>(
        xp, att_src, att_dst, a_src, a_dst, n);
    // CSR build: zero, histogram, scan, scatter
    zero_int2<<<(n + 255) / 256, 256, 0, stream>>>(deg, cursor, n);
    hist_kernel<<<(ET + 255) / 256, 256, 0, stream>>>(dst, deg, E_real, ET);
    scan_kernel<<<1, 256, 0, stream>>>(deg, rowptr, n);
    scatter_kernel<<<(ET + 255) / 256, 256, 0, stream>>>(
        src, dst, rowptr, cursor, sorted_src, E_real, ET);
    // softmax + aggregate + normalize + bias (one block per node)
    gat_aggregate<<<n, 256, 0, stream>>>(
        rowptr, sorted_src, a_src, a_dst, xp, bias_g, xg);
    // out = xg @ W3 + b3
    sgemm_bias_act<<<dim3(gm, 512 / 64), 256, 0, stream>>>(
        xg, W3, b3, out, n, 512, HC, 0);
}

// Round 3
// 587.475 us; speedup vs baseline: 1.8844x; 1.1210x over previous
//
#include <hip/hip_runtime.h>
#include <hip/hip_bf16.h>
#include <float.h>

// Problem constants (from reference)
#define N_NODES 20000
#define LATENT  512
#define HID     256
#define OUT_C   128
#define HEADS   2
#define HC      256   // HEADS*OUT_C
#define NEG_SLOPE 0.2f

// ---------------------------------------------------------------------------
// Tiled fp32 GEMM: C[M,N] = act(A[M,K] @ B[K,N] + bias)
// 128x64 block tile, 256 threads, 8x4 micro-tile per thread, BK=16.
#define BM 128
#define BN 64
#define BK 16
__global__ __launch_bounds__(256) void sgemm_bias_act(
    const float* __restrict__ A, const float* __restrict__ B,
    const float* __restrict__ bias, float* __restrict__ C,
    int M, int N, int K, int relu)
{
    __shared__ float s_a[BK][BM];   // transposed A tile; writes 2-way aliased (free)
    __shared__ float s_b[BK][BN];

    const int tid = threadIdx.x;
    const int tx = tid & 15;        // N dir: 16 x 4 = 64
    const int ty = tid >> 4;        // M dir: 16 x 8 = 128
    const int row0 = blockIdx.x * BM;
    const int col0 = blockIdx.y * BN;

    // A staging: thread -> row ar = tid>>1, 8 cols at ac = (tid&1)*8
    const int ar = tid >> 1;
    const int ac = (tid & 1) * 8;
    const bool a_ok = (row0 + ar) < M;
    const float* Aptr = A + (size_t)(row0 + ar) * K + ac;

    // B staging: thread -> row br, 4 cols at bc
    const int br = tid >> 4;
    const int bc = (tid & 15) * 4;
    const float* Bptr = B + (size_t)br * N + col0 + bc;

    float acc[8][4] = {};

    for (int k0 = 0; k0 < K; k0 += BK) {
        float4 av0 = make_float4(0.f, 0.f, 0.f, 0.f);
        float4 av1 = make_float4(0.f, 0.f, 0.f, 0.f);
        if (a_ok) {
            av0 = *(const float4*)(Aptr + k0);
            av1 = *(const float4*)(Aptr + k0 + 4);
        }
        s_a[ac + 0][ar] = av0.x; s_a[ac + 1][ar] = av0.y;
        s_a[ac + 2][ar] = av0.z; s_a[ac + 3][ar] = av0.w;
        s_a[ac + 4][ar] = av1.x; s_a[ac + 5][ar] = av1.y;
        s_a[ac + 6][ar] = av1.z; s_a[ac + 7][ar] = av1.w;

        *(float4*)(&s_b[br][bc]) = *(const float4*)(Bptr + (size_t)k0 * N);

        __syncthreads();

        #pragma unroll
        for (int k = 0; k < BK; ++k) {
            float a[8], b[4];
            *(float4*)(a)     = *(const float4*)(&s_a[k][ty * 8]);
            *(float4*)(a + 4) = *(const float4*)(&s_a[k][ty * 8 + 4]);
            *(float4*)(b)     = *(const float4*)(&s_b[k][tx * 4]);
            #pragma unroll
            for (int i = 0; i < 8; ++i)
                #pragma unroll
                for (int j = 0; j < 4; ++j)
                    acc[i][j] += a[i] * b[j];
        }
        __syncthreads();
    }

    float4 bg = make_float4(0.f, 0.f, 0.f, 0.f);
    if (bias) bg = *(const float4*)(bias + col0 + tx * 4);
    #pragma unroll
    for (int i = 0; i < 8; ++i) {
        int r = row0 + ty * 8 + i;
        if (r >= M) continue;
        float4 v;
        v.x = acc[i][0] + bg.x;
        v.y = acc[i][1] + bg.y;
        v.z = acc[i][2] + bg.z;
        v.w = acc[i][3] + bg.w;
        if (relu) {
            v.x = fmaxf(v.x, 0.f); v.y = fmaxf(v.y, 0.f);
            v.z = fmaxf(v.z, 0.f); v.w = fmaxf(v.w, 0.f);
        }
        *(float4*)(C + (size_t)r * N + col0 + tx * 4) = v;
    }
}

// ---------------------------------------------------------------------------
// a_src[n,h] = dot(xp[n,h,:], att_src[h,:]); a_dst likewise. One wave per (n,h).
__global__ __launch_bounds__(256) void att_kernel(
    const float* __restrict__ xp, const float* __restrict__ att_src,
    const float* __restrict__ att_dst,
    float* __restrict__ a_src, float* __restrict__ a_dst, int n)
{
    int gw = (blockIdx.x * blockDim.x + threadIdx.x) >> 6;  // global wave id
    int lane = threadIdx.x & 63;
    if (gw >= 2 * n) return;
    int node = gw >> 1, h = gw & 1;
    const float* row = xp + (size_t)node * HC + h * OUT_C;
    const float* as = att_src + h * OUT_C;
    const float* ad = att_dst + h * OUT_C;
    float s1 = row[lane] * as[lane] + row[lane + 64] * as[lane + 64];
    float s2 = row[lane] * ad[lane] + row[lane + 64] * ad[lane + 64];
    #pragma unroll
    for (int off = 32; off > 0; off >>= 1) {
        s1 += __shfl_down(s1, off);
        s2 += __shfl_down(s2, off);
    }
    if (lane == 0) { a_src[gw] = s1; a_dst[gw] = s2; }
}

// ---------------------------------------------------------------------------
// Zero deg + cursor (ws is poisoned 0xAA before every call)
__global__ void zero_int2(int* deg, int* cursor, int n)
{
    int i = blockIdx.x * blockDim.x + threadIdx.x;
    if (i < n) { deg[i] = 0; cursor[i] = 0; }
}

// ---------------------------------------------------------------------------
// Histogram of dst (incl. self loops)
__global__ __launch_bounds__(256) void hist_kernel(
    const int* __restrict__ dst, int* deg, int E_real, int ET)
{
    int e = blockIdx.x * blockDim.x + threadIdx.x;
    if (e >= ET) return;
    int d = (e < E_real) ? dst[e] : (e - E_real);
    atomicAdd(&deg[d], 1);
}

// ---------------------------------------------------------------------------
// Exclusive scan deg[0..n) -> rowptr[0..n]; single block, 256 threads.
__global__ __launch_bounds__(256) void scan_kernel(
    const int* __restrict__ deg, int* __restrict__ rowptr, int n)
{
    __shared__ int part[256];
    __shared__ int scan[257];
    const int t = threadIdx.x;
    const int chunk = (n + 255) / 256;
    const int lo = t * chunk;
    const int hi = min(lo + chunk, n);
    int s = 0;
    for (int i = lo; i < hi; ++i) s += deg[i];
    part[t] = s;
    __syncthreads();
    if (t == 0) {
        int acc = 0;
        scan[0] = 0;
        for (int i = 0; i < 256; ++i) { acc += part[i]; scan[i + 1] = acc; }
    }
    __syncthreads();
    int run = scan[t];
    for (int i = lo; i < hi; ++i) { rowptr[i] = run; run += deg[i]; }
    if (t == 255) rowptr[n] = run;
}

// ---------------------------------------------------------------------------
// Scatter src ids into dst-sorted order
__global__ __launch_bounds__(256) void scatter_kernel(
    const int* __restrict__ src, const int* __restrict__ dst,
    const int* __restrict__ rowptr, int* cursor,
    int* __restrict__ sorted_src, int E_real, int ET)
{
    int e = blockIdx.x * blockDim.x + threadIdx.x;
    if (e >= ET) return;
    int s, d;
    if (e < E_real) { s = src[e]; d = dst[e]; }
    else            { s = e - E_real; d = s; }
    int pos = rowptr[d] + atomicAdd(&cursor[d], 1);
    sorted_src[pos] = s;
}

// ---------------------------------------------------------------------------
// One WAVE per dst node. Thread lane owns 4 channels (float4); head = lane>>5.
// Per 64-edge chunk: exp-weights computed ONCE per edge into LDS, then the
// inner loop is 2 LDS broadcasts + 1 dwordx4 gather + 4 FMA per edge.
__global__ __launch_bounds__(64) void gat_aggregate(
    const int* __restrict__ rowptr, const int* __restrict__ sorted_src,
    const float* __restrict__ a_src, const float* __restrict__ a_dst,
    const float* __restrict__ xp, const float* __restrict__ bias_g,
    float* __restrict__ xg)
{
    __shared__ float s_w[2][64];
    __shared__ int   s_off[64];

    const int d = blockIdx.x;
    const int lane = threadIdx.x;        // 0..63
    const int h = lane >> 5;             // channels 4*lane..4*lane+3 -> head
    const int start = rowptr[d], end = rowptr[d + 1];

    const float ad0 = a_dst[2 * d + 0];
    const float ad1 = a_dst[2 * d + 1];

    // Phase A: per-head max of leaky_relu(a_src[s]+a_dst[d])
    float m0 = -FLT_MAX, m1 = -FLT_MAX;
    for (int e = start + lane; e < end; e += 64) {
        int s = sorted_src[e];
        float v0 = a_src[2 * s + 0] + ad0;
        float v1 = a_src[2 * s + 1] + ad1;
        v0 = (v0 > 0.f) ? v0 : NEG_SLOPE * v0;
        v1 = (v1 > 0.f) ? v1 : NEG_SLOPE * v1;
        m0 = fmaxf(m0, v0);
        m1 = fmaxf(m1, v1);
    }
    #pragma unroll
    for (int off = 32; off > 0; off >>= 1) {
        m0 = fmaxf(m0, __shfl_xor(m0, off));
        m1 = fmaxf(m1, __shfl_xor(m1, off));
    }

    // Phase B: chunked exp-weight precompute + float4 gather-accumulate
    float4 acc = make_float4(0.f, 0.f, 0.f, 0.f);
    float denom = 0.f;
    for (int e0 = start; e0 < end; e0 += 64) {
        int cnt = min(64, end - e0);
        if (lane < cnt) {
            int s = sorted_src[e0 + lane];
            float v0 = a_src[2 * s + 0] + ad0;
            float v1 = a_src[2 * s + 1] + ad1;
            v0 = (v0 > 0.f) ? v0 : NEG_SLOPE * v0;
            v1 = (v1 > 0.f) ? v1 : NEG_SLOPE * v1;
            s_w[0][lane] = expf(v0 - m0);
            s_w[1][lane] = expf(v1 - m1);
            s_off[lane] = s * HC;
        }
        __syncthreads();
        for (int j = 0; j < cnt; ++j) {
            float w = s_w[h][j];
            const float4 v = *(const float4*)(xp + s_off[j] + 4 * lane);
            denom += w;
            acc.x += w * v.x; acc.y += w * v.y;
            acc.z += w * v.z; acc.w += w * v.w;
        }
        __syncthreads();
    }

    float inv = 1.f / fmaxf(denom, 1e-16f);
    int c = 4 * lane;
    float4 bg = *(const float4*)(bias_g + c);
    float4 o;
    o.x = acc.x * inv + bg.x;
    o.y = acc.y * inv + bg.y;
    o.z = acc.z * inv + bg.z;
    o.w = acc.w * inv + bg.w;
    *(float4*)(xg + (size_t)d * HC + c) = o;
}

// ---------------------------------------------------------------------------
extern "C" void kernel_launch(void* const* d_in, const int* in_sizes, int n_in,
                              void* d_out, int out_size, void* d_ws, size_t ws_size,
                              hipStream_t stream)
{
    const float* z       = (const float*)d_in[0];
    const int*   ei      = (const int*)d_in[1];    // [2,E] int32
    const float* W1      = (const float*)d_in[2];
    const float* b1      = (const float*)d_in[3];
    const float* W2      = (const float*)d_in[4];
    const float* b2      = (const float*)d_in[5];
    const float* Wg      = (const float*)d_in[6];
    const float* att_src = (const float*)d_in[7];
    const float* att_dst = (const float*)d_in[8];
    const float* bias_g  = (const float*)d_in[9];
    const float* W3      = (const float*)d_in[10];
    const float* b3      = (const float*)d_in[11];
    float* out = (float*)d_out;

    const int n = N_NODES;
    const int E_real = in_sizes[1] / 2;
    const int ET = E_real + n;                 // edges + self loops
    const int* src = ei;
    const int* dst = ei + E_real;

    // Workspace layout. xg aliases x1 (dead after GEMM2).
    float* ws = (float*)d_ws;
    size_t o = 0;
    float* x1    = ws + o; o += (size_t)n * HID;     // 5.12M
    float* x2    = ws + o; o += (size_t)n * 512;     // 10.24M
    float* xp    = ws + o; o += (size_t)n * HC;      // 5.12M
    float* a_src = ws + o; o += (size_t)2 * n;
    float* a_dst = ws + o; o += (size_t)2 * n;
    int* deg        = (int*)(ws + o); o += (size_t)n;
    int* rowptr     = (int*)(ws + o); o += (size_t)n + 1;
    int* cursor     = (int*)(ws + o); o += (size_t)n;
    int* sorted_src = (int*)(ws + o); o += (size_t)ET;
    float* xg = x1;   // reuse

    const int gmM = (n + BM - 1) / BM;   // 157

    // x1 = relu(z @ W1 + b1)
    sgemm_bias_act<<<dim3(gmM, HID / BN), 256, 0, stream>>>(
        z, W1, b1, x1, n, HID, LATENT, 1);
    // x2 = relu(x1 @ W2 + b2)
    sgemm_bias_act<<<dim3(gmM, 512 / BN), 256, 0, stream>>>(
        x1, W2, b2, x2, n, 512, HID, 1);
    // xp = x2 @ Wg
    sgemm_bias_act<<<dim3(gmM, HC / BN), 256, 0, stream>>>(
        x2, Wg, nullptr, xp, n, HC, 512, 0);
    // attention logits per (node, head)
    att_kernel<<<(2 * n + 3) / 4, 256, 0, stream>>>(
        xp, att_src, att_dst, a_src, a_dst, n);
    // CSR build: zero, histogram, scan, scatter
    zero_int2<<<(n + 255) / 256, 256, 0, stream>>>(deg, cursor, n);
    hist_kernel<<<(ET + 255) / 256, 256, 0, stream>>>(dst, deg, E_real, ET);
    scan_kernel<<<1, 256, 0, stream>>>(deg, rowptr, n);
    scatter_kernel<<<(ET + 255) / 256, 256, 0, stream>>>(
        src, dst, rowptr, cursor, sorted_src, E_real, ET);
    // softmax + aggregate + normalize + bias (one wave per node)
    gat_aggregate<<<n, 64, 0, stream>>>(
        rowptr, sorted_src, a_src, a_dst, xp, bias_g, xg);
    // out = xg @ W3 + b3
    sgemm_bias_act<<<dim3(gmM, 512 / BN), 256, 0, stream>>>(
        xg, W3, b3, out, n, 512, HC, 0);
}

// Round 5
// 474.136 us; speedup vs baseline: 2.3349x; 1.2390x over previous
//
#include <hip/hip_runtime.h>
#include <hip/hip_bf16.h>
#include <float.h>

// Problem constants (from reference)
#define N_NODES 20000
#define LATENT  512
#define HID     256
#define OUT_C   128
#define HEADS   2
#define HC      256   // HEADS*OUT_C
#define NEG_SLOPE 0.2f

typedef __attribute__((ext_vector_type(8))) short short8;  // 8 bf16 = 4 VGPRs
typedef __attribute__((ext_vector_type(4))) float f32x4;

// ---------------------------------------------------------------------------
// fp32 -> (hi, lo) bf16 split: v ~= hi + lo, error ~2^-18 * |v|
__device__ __forceinline__ ushort f2bf(float v) {
    __hip_bfloat16 h = __float2bfloat16(v);
    return *(ushort*)&h;
}
__device__ __forceinline__ float bf2f(ushort u) {
    __hip_bfloat16 h = *(__hip_bfloat16*)&u;
    return __bfloat162float(h);
}
__device__ __forceinline__ void split2(float v, ushort& hi, ushort& lo) {
    hi = f2bf(v);
    lo = f2bf(v - bf2f(hi));
}

// ---------------------------------------------------------------------------
// Split-bf16 MFMA GEMM:  C = act( Ah*Bh + Ah*Bl + Al*Bh + bias )
// A [M,K] as hi/lo bf16 row-major; B passed TRANSPOSED: BT [N,K] hi/lo bf16.
// Block tile 128x128, 4 waves (64x64 each, 4x4 C-frags of 16x16), BK=32.
// Staging: 128x32 bf16 tile = 8KB per array; 256 threads x 2 int4 = 8KB. (R3
// bug: only 1 int4/thread -> half the tile uninitialized -> NaN.)
#define ST 40   // LDS row stride in shorts (32 + 8 pad -> 2-way bank alias, free)

__global__ __launch_bounds__(256) void gemm_split_mfma(
    const ushort* __restrict__ A_hi, const ushort* __restrict__ A_lo,
    const ushort* __restrict__ BT_hi, const ushort* __restrict__ BT_lo,
    const float* __restrict__ bias,
    float* __restrict__ Cf, ushort* __restrict__ C_hi, ushort* __restrict__ C_lo,
    int M, int N, int K, int relu)
{
    __shared__ ushort lds[4 * 128 * ST];   // Ah, Al, Bh, Bl tiles: 40 KB

    const int t = threadIdx.x;
    const int l = t & 63;
    const int w = t >> 6;
    const int wm = (w >> 1) * 64;          // wave M offset in tile
    const int wn = (w & 1) * 64;           // wave N offset in tile
    const int lm = l & 15;
    const int q8 = (l >> 4) * 8;           // frag k offset
    const int q4 = (l >> 4) * 4;           // C frag row offset

    const int row0 = blockIdx.x * 128;
    const int col0 = blockIdx.y * 128;

    // staging: thread t loads 32B (16 bf16) of row sr, col half sc
    const int sr = t >> 1;                 // 0..127
    const int sc = (t & 1) * 16;           // 0 or 16
    const bool a_ok = (row0 + sr) < M;
    const ushort* pAh = A_hi + (size_t)(row0 + sr) * K + sc;
    const ushort* pAl = A_lo + (size_t)(row0 + sr) * K + sc;
    const ushort* pBh = BT_hi + (size_t)(col0 + sr) * K + sc;
    const ushort* pBl = BT_lo + (size_t)(col0 + sr) * K + sc;

    ushort* ldsAh = lds;
    ushort* ldsAl = lds + 128 * ST;
    ushort* ldsBh = lds + 2 * 128 * ST;
    ushort* ldsBl = lds + 3 * 128 * ST;
    const int sa = sr * ST + sc;

    const f32x4 zf = {0.f, 0.f, 0.f, 0.f};
    f32x4 acc[4][4];
    #pragma unroll
    for (int i = 0; i < 4; ++i)
        #pragma unroll
        for (int j = 0; j < 4; ++j) acc[i][j] = zf;

    const int4 zero4 = make_int4(0, 0, 0, 0);
    int4 ra_h0 = a_ok ? *(const int4*)(pAh)     : zero4;
    int4 ra_h1 = a_ok ? *(const int4*)(pAh + 8) : zero4;
    int4 ra_l0 = a_ok ? *(const int4*)(pAl)     : zero4;
    int4 ra_l1 = a_ok ? *(const int4*)(pAl + 8) : zero4;
    int4 rb_h0 = *(const int4*)(pBh);
    int4 rb_h1 = *(const int4*)(pBh + 8);
    int4 rb_l0 = *(const int4*)(pBl);
    int4 rb_l1 = *(const int4*)(pBl + 8);

    for (int k0 = 0; k0 < K; k0 += 32) {
        __syncthreads();   // previous iteration's frag reads done
        *(int4*)&ldsAh[sa] = ra_h0;  *(int4*)&ldsAh[sa + 8] = ra_h1;
        *(int4*)&ldsAl[sa] = ra_l0;  *(int4*)&ldsAl[sa + 8] = ra_l1;
        *(int4*)&ldsBh[sa] = rb_h0;  *(int4*)&ldsBh[sa + 8] = rb_h1;
        *(int4*)&ldsBl[sa] = rb_l0;  *(int4*)&ldsBl[sa + 8] = rb_l1;
        __syncthreads();

        if (k0 + 32 < K) {   // prefetch next chunk while MFMAs run
            const int kk = k0 + 32;
            ra_h0 = a_ok ? *(const int4*)(pAh + kk)     : zero4;
            ra_h1 = a_ok ? *(const int4*)(pAh + kk + 8) : zero4;
            ra_l0 = a_ok ? *(const int4*)(pAl + kk)     : zero4;
            ra_l1 = a_ok ? *(const int4*)(pAl + kk + 8) : zero4;
            rb_h0 = *(const int4*)(pBh + kk);
            rb_h1 = *(const int4*)(pBh + kk + 8);
            rb_l0 = *(const int4*)(pBl + kk);
            rb_l1 = *(const int4*)(pBl + kk + 8);
        }

        short8 bh[4], bl[4];
        #pragma unroll
        for (int ni = 0; ni < 4; ++ni) {
            const int boff = (wn + ni * 16 + lm) * ST + q8;
            bh[ni] = *(const short8*)&ldsBh[boff];
            bl[ni] = *(const short8*)&ldsBl[boff];
        }
        #pragma unroll
        for (int mi = 0; mi < 4; ++mi) {
            const int aoff = (wm + mi * 16 + lm) * ST + q8;
            short8 ah = *(const short8*)&ldsAh[aoff];
            short8 al = *(const short8*)&ldsAl[aoff];
            #pragma unroll
            for (int ni = 0; ni < 4; ++ni) {
                acc[mi][ni] = __builtin_amdgcn_mfma_f32_16x16x32_bf16(ah, bh[ni], acc[mi][ni], 0, 0, 0);
                acc[mi][ni] = __builtin_amdgcn_mfma_f32_16x16x32_bf16(ah, bl[ni], acc[mi][ni], 0, 0, 0);
                acc[mi][ni] = __builtin_amdgcn_mfma_f32_16x16x32_bf16(al, bh[ni], acc[mi][ni], 0, 0, 0);
            }
        }
    }

    // Epilogue. C/D frag: col = lane&15, row = (lane>>4)*4 + reg  [m89/m91]
    #pragma unroll
    for (int mi = 0; mi < 4; ++mi) {
        #pragma unroll
        for (int ni = 0; ni < 4; ++ni) {
            const int col = col0 + wn + ni * 16 + lm;
            const float bv = bias ? bias[col] : 0.f;
            #pragma unroll
            for (int r = 0; r < 4; ++r) {
                const int row = row0 + wm + mi * 16 + q4 + r;
                if (row >= M) continue;
                float v = acc[mi][ni][r] + bv;
                if (relu) v = fmaxf(v, 0.f);
                const size_t idx = (size_t)row * N + col;
                if (Cf) Cf[idx] = v;
                if (C_hi) {
                    ushort h, lo_;
                    split2(v, h, lo_);
                    C_hi[idx] = h;
                    C_lo[idx] = lo_;
                }
            }
        }
    }
}

// ---------------------------------------------------------------------------
// Elementwise fp32 -> hi/lo bf16 split (vectorized x4)
__global__ __launch_bounds__(256) void split_kernel(
    const float* __restrict__ x, ushort* __restrict__ hi,
    ushort* __restrict__ lo, int n4)
{
    int i = blockIdx.x * 256 + threadIdx.x;
    if (i >= n4) return;
    float4 v = ((const float4*)x)[i];
    ushort h0, l0, h1, l1, h2, l2, h3, l3;
    split2(v.x, h0, l0); split2(v.y, h1, l1);
    split2(v.z, h2, l2); split2(v.w, h3, l3);
    ((ushort4*)hi)[i] = make_ushort4(h0, h1, h2, h3);
    ((ushort4*)lo)[i] = make_ushort4(l0, l1, l2, l3);
}

// ---------------------------------------------------------------------------
// W [K,N] fp32 -> WT hi/lo bf16 [N,K] (transpose + split; tiny matrices)
__global__ __launch_bounds__(256) void transpose_split_kernel(
    const float* __restrict__ W, ushort* __restrict__ Th,
    ushort* __restrict__ Tl, int K, int N)
{
    int i = blockIdx.x * 256 + threadIdx.x;
    if (i >= K * N) return;
    int k = i / N, n = i - k * N;
    ushort h, lo_;
    split2(W[i], h, lo_);
    Th[(size_t)n * K + k] = h;
    Tl[(size_t)n * K + k] = lo_;
}

// ---------------------------------------------------------------------------
// a_src[n,h] = dot(xp[n,h,:], att_src[h,:]); a_dst likewise. One wave per (n,h).
__global__ __launch_bounds__(256) void att_kernel(
    const float* __restrict__ xp, const float* __restrict__ att_src,
    const float* __restrict__ att_dst,
    float* __restrict__ a_src, float* __restrict__ a_dst, int n)
{
    int gw = (blockIdx.x * blockDim.x + threadIdx.x) >> 6;
    int lane = threadIdx.x & 63;
    if (gw >= 2 * n) return;
    int node = gw >> 1, h = gw & 1;
    const float* row = xp + (size_t)node * HC + h * OUT_C;
    const float* as = att_src + h * OUT_C;
    const float* ad = att_dst + h * OUT_C;
    float s1 = row[lane] * as[lane] + row[lane + 64] * as[lane + 64];
    float s2 = row[lane] * ad[lane] + row[lane + 64] * ad[lane + 64];
    #pragma unroll
    for (int off = 32; off > 0; off >>= 1) {
        s1 += __shfl_down(s1, off);
        s2 += __shfl_down(s2, off);
    }
    if (lane == 0) { a_src[gw] = s1; a_dst[gw] = s2; }
}

// ---------------------------------------------------------------------------
__global__ void zero_int2(int* deg, int* cursor, int n)
{
    int i = blockIdx.x * blockDim.x + threadIdx.x;
    if (i < n) { deg[i] = 0; cursor[i] = 0; }
}

__global__ __launch_bounds__(256) void hist_kernel(
    const int* __restrict__ dst, int* deg, int E_real, int ET)
{
    int e = blockIdx.x * blockDim.x + threadIdx.x;
    if (e >= ET) return;
    int d = (e < E_real) ? dst[e] : (e - E_real);
    atomicAdd(&deg[d], 1);
}

__global__ __launch_bounds__(256) void scan_kernel(
    const int* __restrict__ deg, int* __restrict__ rowptr, int n)
{
    __shared__ int part[256];
    __shared__ int scan[257];
    const int t = threadIdx.x;
    const int chunk = (n + 255) / 256;
    const int lo = t * chunk;
    const int hi = min(lo + chunk, n);
    int s = 0;
    for (int i = lo; i < hi; ++i) s += deg[i];
    part[t] = s;
    __syncthreads();
    if (t == 0) {
        int acc = 0;
        scan[0] = 0;
        for (int i = 0; i < 256; ++i) { acc += part[i]; scan[i + 1] = acc; }
    }
    __syncthreads();
    int run = scan[t];
    for (int i = lo; i < hi; ++i) { rowptr[i] = run; run += deg[i]; }
    if (t == 255) rowptr[n] = run;
}

__global__ __launch_bounds__(256) void scatter_kernel(
    const int* __restrict__ src, const int* __restrict__ dst,
    const int* __restrict__ rowptr, int* cursor,
    int* __restrict__ sorted_src, int E_real, int ET)
{
    int e = blockIdx.x * blockDim.x + threadIdx.x;
    if (e >= ET) return;
    int s, d;
    if (e < E_real) { s = src[e]; d = dst[e]; }
    else            { s = e - E_real; d = s; }
    int pos = rowptr[d] + atomicAdd(&cursor[d], 1);
    sorted_src[pos] = s;
}

// ---------------------------------------------------------------------------
// One WAVE per dst node; lane owns 4 channels (float4); head = lane>>5.
// Emits xg directly as hi/lo bf16 for GEMM4's A operand.
__global__ __launch_bounds__(64) void gat_aggregate(
    const int* __restrict__ rowptr, const int* __restrict__ sorted_src,
    const float* __restrict__ a_src, const float* __restrict__ a_dst,
    const float* __restrict__ xp, const float* __restrict__ bias_g,
    ushort* __restrict__ xg_hi, ushort* __restrict__ xg_lo)
{
    __shared__ float s_w[2][64];
    __shared__ int   s_off[64];

    const int d = blockIdx.x;
    const int lane = threadIdx.x;
    const int h = lane >> 5;
    const int start = rowptr[d], end = rowptr[d + 1];

    const float ad0 = a_dst[2 * d + 0];
    const float ad1 = a_dst[2 * d + 1];

    float m0 = -FLT_MAX, m1 = -FLT_MAX;
    for (int e = start + lane; e < end; e += 64) {
        int s = sorted_src[e];
        float v0 = a_src[2 * s + 0] + ad0;
        float v1 = a_src[2 * s + 1] + ad1;
        v0 = (v0 > 0.f) ? v0 : NEG_SLOPE * v0;
        v1 = (v1 > 0.f) ? v1 : NEG_SLOPE * v1;
        m0 = fmaxf(m0, v0);
        m1 = fmaxf(m1, v1);
    }
    #pragma unroll
    for (int off = 32; off > 0; off >>= 1) {
        m0 = fmaxf(m0, __shfl_xor(m0, off));
        m1 = fmaxf(m1, __shfl_xor(m1, off));
    }

    float4 acc = make_float4(0.f, 0.f, 0.f, 0.f);
    float denom = 0.f;
    for (int e0 = start; e0 < end; e0 += 64) {
        int cnt = min(64, end - e0);
        if (lane < cnt) {
            int s = sorted_src[e0 + lane];
            float v0 = a_src[2 * s + 0] + ad0;
            float v1 = a_src[2 * s + 1] + ad1;
            v0 = (v0 > 0.f) ? v0 : NEG_SLOPE * v0;
            v1 = (v1 > 0.f) ? v1 : NEG_SLOPE * v1;
            s_w[0][lane] = expf(v0 - m0);
            s_w[1][lane] = expf(v1 - m1);
            s_off[lane] = s * HC;
        }
        __syncthreads();
        for (int j = 0; j < cnt; ++j) {
            float w = s_w[h][j];
            const float4 v = *(const float4*)(xp + s_off[j] + 4 * lane);
            denom += w;
            acc.x += w * v.x; acc.y += w * v.y;
            acc.z += w * v.z; acc.w += w * v.w;
        }
        __syncthreads();
    }

    float inv = 1.f / fmaxf(denom, 1e-16f);
    int c = 4 * lane;
    float4 bg = *(const float4*)(bias_g + c);
    float o0 = acc.x * inv + bg.x;
    float o1 = acc.y * inv + bg.y;
    float o2 = acc.z * inv + bg.z;
    float o3 = acc.w * inv + bg.w;
    ushort h0, l0, h1, l1, h2, l2, h3, l3;
    split2(o0, h0, l0); split2(o1, h1, l1);
    split2(o2, h2, l2); split2(o3, h3, l3);
    const size_t base = ((size_t)d * HC + c) >> 2;
    ((ushort4*)xg_hi)[base] = make_ushort4(h0, h1, h2, h3);
    ((ushort4*)xg_lo)[base] = make_ushort4(l0, l1, l2, l3);
}

// ---------------------------------------------------------------------------
extern "C" void kernel_launch(void* const* d_in, const int* in_sizes, int n_in,
                              void* d_out, int out_size, void* d_ws, size_t ws_size,
                              hipStream_t stream)
{
    const float* z       = (const float*)d_in[0];
    const int*   ei      = (const int*)d_in[1];    // [2,E] int32
    const float* W1      = (const float*)d_in[2];
    const float* b1      = (const float*)d_in[3];
    const float* W2      = (const float*)d_in[4];
    const float* b2      = (const float*)d_in[5];
    const float* Wg      = (const float*)d_in[6];
    const float* att_src = (const float*)d_in[7];
    const float* att_dst = (const float*)d_in[8];
    const float* bias_g  = (const float*)d_in[9];
    const float* W3      = (const float*)d_in[10];
    const float* b3      = (const float*)d_in[11];
    float* out = (float*)d_out;

    const int n = N_NODES;
    const int E_real = in_sizes[1] / 2;
    const int ET = E_real + n;
    const int* src = ei;
    const int* dst = ei + E_real;

    // Workspace layout (bytes, 64B-aligned regions). Aliases:
    //   z_hi/z_lo  (dead after GEMM1)  ≡ x2_hi/x2_lo
    //   x1_hi/x1_lo (dead after GEMM2) ≡ xg_hi/xg_lo
    char* p = (char*)d_ws;
    auto alloc = [&](size_t bytes) {
        char* r = p;
        p += (bytes + 63) & ~(size_t)63;
        return r;
    };
    ushort* z_hi  = (ushort*)alloc((size_t)n * LATENT * 2);   // 20.48 MB
    ushort* z_lo  = (ushort*)alloc((size_t)n * LATENT * 2);
    ushort* x1_hi = (ushort*)alloc((size_t)n * HID * 2);      // 10.24 MB
    ushort* x1_lo = (ushort*)alloc((size_t)n * HID * 2);
    float*  xp    = (float*)alloc((size_t)n * HC * 4);        // 20.48 MB
    ushort* W1T_h = (ushort*)alloc((size_t)LATENT * HID * 2);
    ushort* W1T_l = (ushort*)alloc((size_t)LATENT * HID * 2);
    ushort* W2T_h = (ushort*)alloc((size_t)HID * 512 * 2);
    ushort* W2T_l = (ushort*)alloc((size_t)HID * 512 * 2);
    ushort* WgT_h = (ushort*)alloc((size_t)512 * HC * 2);
    ushort* WgT_l = (ushort*)alloc((size_t)512 * HC * 2);
    ushort* W3T_h = (ushort*)alloc((size_t)HC * 512 * 2);
    ushort* W3T_l = (ushort*)alloc((size_t)HC * 512 * 2);
    float* a_src = (float*)alloc((size_t)2 * n * 4);
    float* a_dst = (float*)alloc((size_t)2 * n * 4);
    int* deg        = (int*)alloc((size_t)n * 4);
    int* rowptr     = (int*)alloc(((size_t)n + 1) * 4);
    int* cursor     = (int*)alloc((size_t)n * 4);
    int* sorted_src = (int*)alloc((size_t)ET * 4);
    ushort* x2_hi = z_hi;    // reuse
    ushort* x2_lo = z_lo;
    ushort* xg_hi = x1_hi;   // reuse
    ushort* xg_lo = x1_lo;

    const int gmM = (n + 127) / 128;   // 157

    // input/weight splits
    split_kernel<<<(n * LATENT / 4 + 255) / 256, 256, 0, stream>>>(
        z, z_hi, z_lo, n * LATENT / 4);
    transpose_split_kernel<<<(LATENT * HID + 255) / 256, 256, 0, stream>>>(
        W1, W1T_h, W1T_l, LATENT, HID);
    transpose_split_kernel<<<(HID * 512 + 255) / 256, 256, 0, stream>>>(
        W2, W2T_h, W2T_l, HID, 512);
    transpose_split_kernel<<<(512 * HC + 255) / 256, 256, 0, stream>>>(
        Wg, WgT_h, WgT_l, 512, HC);
    transpose_split_kernel<<<(HC * 512 + 255) / 256, 256, 0, stream>>>(
        W3, W3T_h, W3T_l, HC, 512);

    // GEMM1: x1 = relu(z @ W1 + b1)   [20000,512]x[512,256] -> split only
    gemm_split_mfma<<<dim3(gmM, HID / 128), 256, 0, stream>>>(
        z_hi, z_lo, W1T_h, W1T_l, b1, nullptr, x1_hi, x1_lo, n, HID, LATENT, 1);
    // GEMM2: x2 = relu(x1 @ W2 + b2)  [20000,256]x[256,512] -> split only
    gemm_split_mfma<<<dim3(gmM, 512 / 128), 256, 0, stream>>>(
        x1_hi, x1_lo, W2T_h, W2T_l, b2, nullptr, x2_hi, x2_lo, n, 512, HID, 1);
    // GEMM3: xp = x2 @ Wg             [20000,512]x[512,256] -> fp32 only
    gemm_split_mfma<<<dim3(gmM, HC / 128), 256, 0, stream>>>(
        x2_hi, x2_lo, WgT_h, WgT_l, nullptr, xp, nullptr, nullptr, n, HC, 512, 0);

    // attention logits
    att_kernel<<<(2 * n + 3) / 4, 256, 0, stream>>>(
        xp, att_src, att_dst, a_src, a_dst, n);
    // CSR build
    zero_int2<<<(n + 255) / 256, 256, 0, stream>>>(deg, cursor, n);
    hist_kernel<<<(ET + 255) / 256, 256, 0, stream>>>(dst, deg, E_real, ET);
    scan_kernel<<<1, 256, 0, stream>>>(deg, rowptr, n);
    scatter_kernel<<<(ET + 255) / 256, 256, 0, stream>>>(
        src, dst, rowptr, cursor, sorted_src, E_real, ET);
    // softmax + aggregate -> xg (split)
    gat_aggregate<<<n, 64, 0, stream>>>(
        rowptr, sorted_src, a_src, a_dst, xp, bias_g, xg_hi, xg_lo);

    // GEMM4: out = xg @ W3 + b3       [20000,256]x[256,512] -> fp32
    gemm_split_mfma<<<dim3(gmM, 512 / 128), 256, 0, stream>>>(
        xg_hi, xg_lo, W3T_h, W3T_l, b3, out, nullptr, nullptr, n, 512, HC, 0);
}